// Round 1
// 312.364 us; speedup vs baseline: 1.0068x; 1.0068x over previous
//
#include <hip/hip_runtime.h>

namespace {
constexpr int Bb = 512, Nn = 196, Cc = 384, CT = 16, TPB = 128;
// Unified LDS layout: per-channel row of 14 groups of 16 floats (u-major, v in 0..13,
// slots 14/15 pad), row stride 228 floats. 228 % 32 == 4 -> consecutive channels land
// on bank offsets {0,4,...,28}: 16 rows = 8 bank-pairs, 2-way aliasing = free (m136).
// Phase 1 (S view): U[c*RST + u*16 + v] = x[u*14+v][c]
// Phase 2 (A view): U[c*RST + p*16 + w] = Re A, ... + w + 8 = Im A
constexpr int RST = 228;
constexpr int USZ = CT * RST;   // 3648 floats = 14.25 KiB

constexpr float C7t[7] = {1.f, 0.6234898018587335f, -0.2225209339563144f,
                          -0.9009688679024191f, -0.9009688679024191f,
                          -0.2225209339563144f, 0.6234898018587335f};
constexpr float S7t[7] = {0.f, 0.7818314824680298f, 0.9749279121818236f,
                          0.4338837391175581f, -0.4338837391175581f,
                          -0.9749279121818236f, -0.7818314824680298f};
constexpr float C14t[14] = {1.f, 0.9009688679024191f, 0.6234898018587336f, 0.2225209339563144f,
                            -0.2225209339563144f, -0.6234898018587336f, -0.9009688679024191f, -1.f,
                            -0.9009688679024191f, -0.6234898018587336f, -0.2225209339563144f,
                            0.2225209339563144f, 0.6234898018587336f, 0.9009688679024191f};
constexpr float S14t[14] = {0.f, 0.4338837391175581f, 0.7818314824680298f, 0.9749279121818236f,
                            0.9749279121818236f, 0.7818314824680298f, 0.4338837391175581f, 0.f,
                            -0.4338837391175581f, -0.7818314824680298f, -0.9749279121818236f,
                            -0.9749279121818236f, -0.7818314824680298f, -0.4338837391175581f};
}

// Length-7 complex DFT via conjugate-pair symmetry. SG=+1 forward, SG=-1 inverse.
template<int SG>
__device__ __forceinline__ void dft7(const float* vr, const float* vi, float* Er, float* Ei) {
  const float P1r = vr[1] + vr[6], M1r = vr[1] - vr[6];
  const float P1i = vi[1] + vi[6], M1i = vi[1] - vi[6];
  const float P2r = vr[2] + vr[5], M2r = vr[2] - vr[5];
  const float P2i = vi[2] + vi[5], M2i = vi[2] - vi[5];
  const float P3r = vr[3] + vr[4], M3r = vr[3] - vr[4];
  const float P3i = vi[3] + vi[4], M3i = vi[3] - vi[4];
  Er[0] = vr[0] + P1r + P2r + P3r;
  Ei[0] = vi[0] + P1i + P2i + P3i;
#pragma unroll
  for (int k = 1; k < 7; ++k) {
    const float c1 = C7t[k], c2 = C7t[(2 * k) % 7], c3 = C7t[(3 * k) % 7];
    const float s1 = SG * S7t[k], s2 = SG * S7t[(2 * k) % 7], s3 = SG * S7t[(3 * k) % 7];
    float er = fmaf(P1r, c1, vr[0]);
    er = fmaf(P2r, c2, er);
    er = fmaf(P3r, c3, er);
    er = fmaf(M1i, s1, er);
    er = fmaf(M2i, s2, er);
    er = fmaf(M3i, s3, er);
    float ei = fmaf(P1i, c1, vi[0]);
    ei = fmaf(P2i, c2, ei);
    ei = fmaf(P3i, c3, ei);
    ei = fmaf(M1r, -s1, ei);
    ei = fmaf(M2r, -s2, ei);
    ei = fmaf(M3r, -s3, ei);
    Er[k] = er; Ei[k] = ei;
  }
}

// __launch_bounds__(128, 4): LDS (14.8 KB) caps us at 8-11 blocks/CU anyway, so declare
// the 4-waves/EU target -> VGPR budget 128, eliminating the scratch spills the default
// occupancy heuristic forced at 44 VGPRs.
__global__ __launch_bounds__(TPB, 4) void gf_kernel(const float* __restrict__ x,
                                                    const float* __restrict__ wt,
                                                    float* __restrict__ out) {
  __shared__ float U[USZ];
  __shared__ float Ct[14], St[14];

  const int tid = threadIdx.x;
  const int b   = blockIdx.y;          // grid = (c-tiles, batch): tiles of one batch
  const int c0  = blockIdx.x * CT;     // launch adjacently -> shared 128B L2 lines

  if (tid < 14) { Ct[tid] = C14t[tid]; St[tid] = S14t[tid]; }

  // ---- stage 0: global -> LDS (transposed), float4 loads ----
  const float* xb = x + (size_t)b * (Nn * Cc) + c0;
#pragma unroll
  for (int k = 0; k < 7; ++k) {
    const int i = tid + k * TPB;
    if (i < Nn * 4) {
      const int n = i >> 2, g = (i & 3) << 2;
      const float4 q = *reinterpret_cast<const float4*>(&xb[n * Cc + g]);
      const int u = n / 14;            // row slot = u*16 + v = n + 2u
      float* Un = &U[n + 2 * u];
      Un[(g + 0) * RST] = q.x;
      Un[(g + 1) * RST] = q.y;
      Un[(g + 2) * RST] = q.z;
      Un[(g + 3) * RST] = q.w;
    }
  }
  __syncthreads();

  const int cl = tid & 15;
  const int w  = tid >> 4;

  // twiddles cos/sin(2*pi*w*v/14) for v=1..6 (v=0 is trivially (1,0))
  float cw[7], sw[7];
  {
    int idx = w;
#pragma unroll
    for (int v = 1; v < 7; ++v) {
      cw[v] = Ct[idx]; sw[v] = St[idx];
      idx += w; if (idx >= 14) idx -= 14;
    }
  }
  const float sg = (w & 1) ? -1.f : 1.f;   // e^{-i pi w} parity-fold sign

  // ---- stage 1: V[u] = sum_{v=0..6} (S[u][v] + sg*S[u][v+7]) e^{-2pi i w v/14} ----
  float Vr[14], Vi[14];
  const float* Srow = &U[cl * RST];
#pragma unroll
  for (int u = 0; u < 14; ++u) {
    const float4 q0 = *reinterpret_cast<const float4*>(&Srow[u * 16 + 0]);
    const float4 q1 = *reinterpret_cast<const float4*>(&Srow[u * 16 + 4]);
    const float4 q2 = *reinterpret_cast<const float4*>(&Srow[u * 16 + 8]);
    const float4 q3 = *reinterpret_cast<const float4*>(&Srow[u * 16 + 12]); // .z/.w = pad
    const float f0 = fmaf(sg, q1.w, q0.x);
    const float f1 = fmaf(sg, q2.x, q0.y);
    const float f2 = fmaf(sg, q2.y, q0.z);
    const float f3 = fmaf(sg, q2.z, q0.w);
    const float f4 = fmaf(sg, q2.w, q1.x);
    const float f5 = fmaf(sg, q3.x, q1.y);
    const float f6 = fmaf(sg, q3.y, q1.z);
    float vr = f0, vi = 0.f;
    vr = fmaf(f1, cw[1], vr); vi = fmaf(f1, -sw[1], vi);
    vr = fmaf(f2, cw[2], vr); vi = fmaf(f2, -sw[2], vi);
    vr = fmaf(f3, cw[3], vr); vi = fmaf(f3, -sw[3], vi);
    vr = fmaf(f4, cw[4], vr); vi = fmaf(f4, -sw[4], vi);
    vr = fmaf(f5, cw[5], vr); vi = fmaf(f5, -sw[5], vi);
    vr = fmaf(f6, cw[6], vr); vi = fmaf(f6, -sw[6], vi);
    Vr[u] = vr; Vi[u] = vi;
  }

  // issue weight loads BEFORE the barrier so they're in flight across it
  const float2* wp = reinterpret_cast<const float2*>(wt) + ((size_t)w * Cc + c0 + cl);
  float2 wreg[14];
#pragma unroll
  for (int h = 0; h < 14; ++h) wreg[h] = wp[(size_t)h * (8 * Cc)];

  __syncthreads();   // S fully read; U may now be overwritten as A

  // ---- stage 2: X = DFT14(V), radix-2 (even/odd u) ----
  float evr[7], evi[7], odr[7], odi[7];
#pragma unroll
  for (int t = 0; t < 7; ++t) {
    evr[t] = Vr[2 * t];     evi[t] = Vi[2 * t];
    odr[t] = Vr[2 * t + 1]; odi[t] = Vi[2 * t + 1];
  }
  float Er[7], Ei[7], Qr[7], Qi[7];
  dft7<1>(evr, evi, Er, Ei);
  dft7<1>(odr, odi, Qr, Qi);
  float Xr[14], Xi[14];
  Xr[0] = Er[0] + Qr[0]; Xi[0] = Ei[0] + Qi[0];
  Xr[7] = Er[0] - Qr[0]; Xi[7] = Ei[0] - Qi[0];
#pragma unroll
  for (int h = 1; h < 7; ++h) {
    const float c = C14t[h], s = S14t[h];
    const float Tr = fmaf(Qr[h], c,  Qi[h] * s);   // omega14^h * O
    const float Ti = fmaf(Qi[h], c, -Qr[h] * s);
    Xr[h] = Er[h] + Tr;     Xi[h] = Ei[h] + Ti;
    Xr[h + 7] = Er[h] - Tr; Xi[h + 7] = Ei[h] - Ti;
  }

  // ---- stage 3: Y = X * W, with m_w/196 scale folded in ----
  const float scale = ((w == 0 || w == 7) ? 1.f : 2.f) / 196.f;
  float Yr[14], Yi[14];
#pragma unroll
  for (int h = 0; h < 14; ++h) {
    const float wr = wreg[h].x, wi = wreg[h].y;
    Yr[h] = (Xr[h] * wr - Xi[h] * wi) * scale;
    Yi[h] = (Xr[h] * wi + Xi[h] * wr) * scale;
  }

  // ---- stage 4: A[p] = sum_h Y[h] e^{+2pi i p h/14}, radix-2; store to LDS A-view ----
#pragma unroll
  for (int t = 0; t < 7; ++t) {
    evr[t] = Yr[2 * t];     evi[t] = Yi[2 * t];
    odr[t] = Yr[2 * t + 1]; odi[t] = Yi[2 * t + 1];
  }
  dft7<-1>(evr, evi, Er, Ei);
  dft7<-1>(odr, odi, Qr, Qi);
  float* Ap = &U[cl * RST + w];
  Ap[0]            = Er[0] + Qr[0];  Ap[8]            = Ei[0] + Qi[0];
  Ap[7 * 16]       = Er[0] - Qr[0];  Ap[7 * 16 + 8]   = Ei[0] - Qi[0];
#pragma unroll
  for (int p = 1; p < 7; ++p) {
    const float c = C14t[p], s = S14t[p];
    const float Tr = fmaf(Qr[p], c, -Qi[p] * s);   // conj(omega14^p) * O
    const float Ti = fmaf(Qi[p], c,  Qr[p] * s);
    Ap[p * 16]           = Er[p] + Tr;  Ap[p * 16 + 8]       = Ei[p] + Ti;
    Ap[(p + 7) * 16]     = Er[p] - Tr;  Ap[(p + 7) * 16 + 8] = Ei[p] - Ti;
  }
  __syncthreads();

  // ---- epilogue: thread per (p,c); q<->14-q symmetry shares cos/sin sums ----
  float* ob = out + (size_t)b * (Nn * Cc) + c0;
#pragma unroll
  for (int r = 0; r < 2; ++r) {
    const int e = tid + r * TPB;
    if (e < 14 * CT) {
      const int c2 = e & 15, p = e >> 4;
      const float* ap = &U[c2 * RST + p * 16];
      float a[16];
      *reinterpret_cast<float4*>(&a[0])  = *reinterpret_cast<const float4*>(&ap[0]);
      *reinterpret_cast<float4*>(&a[4])  = *reinterpret_cast<const float4*>(&ap[4]);
      *reinterpret_cast<float4*>(&a[8])  = *reinterpret_cast<const float4*>(&ap[8]);
      *reinterpret_cast<float4*>(&a[12]) = *reinterpret_cast<const float4*>(&ap[12]);
      float* op = ob + (p * 14) * Cc + c2;
      // q = 0: sum of Re; q = 7: alternating sum of Re (sin terms vanish)
      op[0]       = ((a[0] + a[7]) + (a[1] + a[2])) + ((a[3] + a[4]) + (a[5] + a[6]));
      op[7 * Cc]  = ((a[0] - a[7]) - (a[1] - a[2])) - ((a[3] - a[4]) + (a[5] - a[6]));
#pragma unroll
      for (int q = 1; q < 7; ++q) {
        float cs = (q & 1) ? (a[0] - a[7]) : (a[0] + a[7]);
        float ss = 0.f;
#pragma unroll
        for (int w2 = 1; w2 < 7; ++w2) {
          cs = fmaf(a[w2], C14t[(w2 * q) % 14], cs);
          ss = fmaf(a[8 + w2], S14t[(w2 * q) % 14], ss);
        }
        op[q * Cc]        = cs - ss;
        op[(14 - q) * Cc] = cs + ss;
      }
    }
  }
}

extern "C" void kernel_launch(void* const* d_in, const int* in_sizes, int n_in,
                              void* d_out, int out_size, void* d_ws, size_t ws_size,
                              hipStream_t stream) {
  const float* x  = (const float*)d_in[0];
  const float* wt = (const float*)d_in[1];
  float* out      = (float*)d_out;
  dim3 grid(Cc / CT, Bb);
  gf_kernel<<<grid, TPB, 0, stream>>>(x, wt, out);
}

// Round 2
// 306.542 us; speedup vs baseline: 1.0259x; 1.0190x over previous
//
#include <hip/hip_runtime.h>

namespace {
constexpr int Bb = 512, Nn = 196, Cc = 384, CT = 16, TPB = 128, NB = 4;
// LDS row stride 228 floats (228 % 32 == 4): 16 channel-rows spread across bank
// pairs, 2-way aliasing = free. Two buffers (pipeline double-buffer).
// S view (per buffer): U[c*RST + u*16 + vp]     = x[u*14+vp][c] + x[u*14+vp+7][c]  (f+)
//                      U[c*RST + u*16 + 8 + vp] = x[u*14+vp][c] - x[u*14+vp+7][c]  (f-)
//   (even-w threads consume f+, odd-w consume f-; slots 7/15 are pad)
// A view (per buffer): U[c*RST + p*16 + w] = Re A_p(w), ... + 8 = Im A_p(w)
constexpr int RST = 228;
constexpr int USZ = CT * RST;   // 3648 floats per buffer

constexpr float C7t[7] = {1.f, 0.6234898018587335f, -0.2225209339563144f,
                          -0.9009688679024191f, -0.9009688679024191f,
                          -0.2225209339563144f, 0.6234898018587335f};
constexpr float S7t[7] = {0.f, 0.7818314824680298f, 0.9749279121818236f,
                          0.4338837391175581f, -0.4338837391175581f,
                          -0.9749279121818236f, -0.7818314824680298f};
constexpr float C14t[14] = {1.f, 0.9009688679024191f, 0.6234898018587336f, 0.2225209339563144f,
                            -0.2225209339563144f, -0.6234898018587336f, -0.9009688679024191f, -1.f,
                            -0.9009688679024191f, -0.6234898018587336f, -0.2225209339563144f,
                            0.2225209339563144f, 0.6234898018587336f, 0.9009688679024191f};
constexpr float S14t[14] = {0.f, 0.4338837391175581f, 0.7818314824680298f, 0.9749279121818236f,
                            0.9749279121818236f, 0.7818314824680298f, 0.4338837391175581f, 0.f,
                            -0.4338837391175581f, -0.7818314824680298f, -0.9749279121818236f,
                            -0.9749279121818236f, -0.7818314824680298f, -0.4338837391175581f};
}

// Length-7 complex DFT via conjugate-pair symmetry. SG=+1 forward, SG=-1 inverse.
template<int SG>
__device__ __forceinline__ void dft7(const float* vr, const float* vi, float* Er, float* Ei) {
  const float P1r = vr[1] + vr[6], M1r = vr[1] - vr[6];
  const float P1i = vi[1] + vi[6], M1i = vi[1] - vi[6];
  const float P2r = vr[2] + vr[5], M2r = vr[2] - vr[5];
  const float P2i = vi[2] + vi[5], M2i = vi[2] - vi[5];
  const float P3r = vr[3] + vr[4], M3r = vr[3] - vr[4];
  const float P3i = vi[3] + vi[4], M3i = vi[3] - vi[4];
  Er[0] = vr[0] + P1r + P2r + P3r;
  Ei[0] = vi[0] + P1i + P2i + P3i;
#pragma unroll
  for (int k = 1; k < 7; ++k) {
    const float c1 = C7t[k], c2 = C7t[(2 * k) % 7], c3 = C7t[(3 * k) % 7];
    const float s1 = SG * S7t[k], s2 = SG * S7t[(2 * k) % 7], s3 = SG * S7t[(3 * k) % 7];
    float er = fmaf(P1r, c1, vr[0]);
    er = fmaf(P2r, c2, er);
    er = fmaf(P3r, c3, er);
    er = fmaf(M1i, s1, er);
    er = fmaf(M2i, s2, er);
    er = fmaf(M3i, s3, er);
    float ei = fmaf(P1i, c1, vi[0]);
    ei = fmaf(P2i, c2, ei);
    ei = fmaf(P3i, c3, ei);
    ei = fmaf(M1r, -s1, ei);
    ei = fmaf(M2r, -s2, ei);
    ei = fmaf(M3r, -s3, ei);
    Er[k] = er; Ei[k] = ei;
  }
}

// launch_bounds(128, 2): LDS (29.3 KB, double-buffered) caps occupancy at 5
// blocks/CU = 10 waves; give the allocator 256 VGPRs so the held pipeline state
// (wreg 28 + staging 32 + DFT working set) never spills.
__global__ __launch_bounds__(TPB, 2) void gf_kernel(const float* __restrict__ x,
                                                    const float* __restrict__ wt,
                                                    float* __restrict__ out) {
  __shared__ float U[2][USZ];
  __shared__ float Ct[14], St[14];

  const int tid = threadIdx.x;
  const int c0  = blockIdx.x * CT;     // adjacent blocks share 128B L2 lines
  const int b0  = blockIdx.y * NB;

  if (tid < 14) { Ct[tid] = C14t[tid]; St[tid] = S14t[tid]; }

  const int cl = tid & 15;
  const int w  = tid >> 4;

  // ---- staging: slot j = tid + 128k (j < 392); g_=(j&3)*4 channel group,
  //      pair = j>>2, u = pair/7, vp = pair%7; loads rows n1=14u+vp, n2=n1+7 ----
  const float* xb0 = x + (size_t)b0 * (Nn * Cc) + c0;
  float4 sA[4], sB[4];

  auto stage_load = [&](const float* xb) {
#pragma unroll
    for (int k = 0; k < 4; ++k) {
      const int j = tid + k * TPB;
      if (j < 392) {
        const int g_ = (j & 3) << 2;
        const int pr = j >> 2;
        const int u  = pr / 7, vp = pr - u * 7;
        const int n1 = u * 14 + vp;
        sA[k] = *reinterpret_cast<const float4*>(&xb[n1 * Cc + g_]);
        sB[k] = *reinterpret_cast<const float4*>(&xb[(n1 + 7) * Cc + g_]);
      }
    }
  };
  auto stage_write = [&](int buf) {
#pragma unroll
    for (int k = 0; k < 4; ++k) {
      const int j = tid + k * TPB;
      if (j < 392) {
        const int g_ = (j & 3) << 2;
        const int pr = j >> 2;
        const int u  = pr / 7, vp = pr - u * 7;
        float* Up = &U[buf][g_ * RST + u * 16 + vp];
        const float a0 = sA[k].x, e0 = sB[k].x;
        Up[0]           = a0 + e0;  Up[8]           = a0 - e0;
        const float a1 = sA[k].y, e1 = sB[k].y;
        Up[RST]         = a1 + e1;  Up[RST + 8]     = a1 - e1;
        const float a2 = sA[k].z, e2 = sB[k].z;
        Up[2 * RST]     = a2 + e2;  Up[2 * RST + 8] = a2 - e2;
        const float a3 = sA[k].w, e3 = sB[k].w;
        Up[3 * RST]     = a3 + e3;  Up[3 * RST + 8] = a3 - e3;
      }
    }
  };

  // ---- prologue: stage tile 0; hoist weight loads (same for all NB batches) ----
  stage_load(xb0);
  const float2* wp = reinterpret_cast<const float2*>(wt) + ((size_t)w * Cc + c0 + cl);
  float2 wreg[14];
#pragma unroll
  for (int h = 0; h < 14; ++h) wreg[h] = wp[(size_t)h * (8 * Cc)];
  stage_write(0);
  __syncthreads();

  // per-thread twiddles cos/sin(2*pi*w*v/14), v=1..6
  float cw[7], sw[7];
  {
    int idx = w;
#pragma unroll
    for (int v = 1; v < 7; ++v) {
      cw[v] = Ct[idx]; sw[v] = St[idx];
      idx += w; if (idx >= 14) idx -= 14;
    }
  }
  const int par8 = (w & 1) * 8;        // f+ block vs f- block
  const float scale = ((w == 0 || w == 7) ? 1.f : 2.f) / 196.f;

  int cur = 0;
  for (int t = 0; t < NB; ++t) {
    // ---- stage 1: V[u] = sum_{vp=0..6} f[u][vp] e^{-2pi i w vp/14} ----
    float Vr[14], Vi[14];
    const float* Fr = &U[cur][cl * RST + par8];
#pragma unroll
    for (int u = 0; u < 14; ++u) {
      const float4 q0 = *reinterpret_cast<const float4*>(&Fr[u * 16]);
      const float4 q1 = *reinterpret_cast<const float4*>(&Fr[u * 16 + 4]); // .w = pad
      float vr = q0.x, vi = 0.f;
      vr = fmaf(q0.y, cw[1], vr); vi = fmaf(q0.y, -sw[1], vi);
      vr = fmaf(q0.z, cw[2], vr); vi = fmaf(q0.z, -sw[2], vi);
      vr = fmaf(q0.w, cw[3], vr); vi = fmaf(q0.w, -sw[3], vi);
      vr = fmaf(q1.x, cw[4], vr); vi = fmaf(q1.x, -sw[4], vi);
      vr = fmaf(q1.y, cw[5], vr); vi = fmaf(q1.y, -sw[5], vi);
      vr = fmaf(q1.z, cw[6], vr); vi = fmaf(q1.z, -sw[6], vi);
      Vr[u] = vr; Vi[u] = vi;
    }

    // prefetch next tile's x into registers (in flight across B1 + compute)
    if (t + 1 < NB) stage_load(xb0 + (size_t)(t + 1) * (Nn * Cc));

    __syncthreads();   // B1: S(t) consumed -> buf[cur] reusable as A(t)

    // ---- stage 2: X = DFT14(V), radix-2 ----
    float evr[7], evi[7], odr[7], odi[7];
#pragma unroll
    for (int i2 = 0; i2 < 7; ++i2) {
      evr[i2] = Vr[2 * i2];     evi[i2] = Vi[2 * i2];
      odr[i2] = Vr[2 * i2 + 1]; odi[i2] = Vi[2 * i2 + 1];
    }
    float Er[7], Ei[7], Qr[7], Qi[7];
    dft7<1>(evr, evi, Er, Ei);
    dft7<1>(odr, odi, Qr, Qi);
    float Xr[14], Xi[14];
    Xr[0] = Er[0] + Qr[0]; Xi[0] = Ei[0] + Qi[0];
    Xr[7] = Er[0] - Qr[0]; Xi[7] = Ei[0] - Qi[0];
#pragma unroll
    for (int h = 1; h < 7; ++h) {
      const float c = C14t[h], s = S14t[h];
      const float Tr = fmaf(Qr[h], c,  Qi[h] * s);   // omega14^h * O
      const float Ti = fmaf(Qi[h], c, -Qr[h] * s);
      Xr[h] = Er[h] + Tr;     Xi[h] = Ei[h] + Ti;
      Xr[h + 7] = Er[h] - Tr; Xi[h + 7] = Ei[h] - Ti;
    }

    // ---- stage 3: Y = X * W (scale folded) ----
    float Yr[14], Yi[14];
#pragma unroll
    for (int h = 0; h < 14; ++h) {
      const float wr = wreg[h].x, wi = wreg[h].y;
      Yr[h] = (Xr[h] * wr - Xi[h] * wi) * scale;
      Yi[h] = (Xr[h] * wi + Xi[h] * wr) * scale;
    }

    // ---- stage 4: A[p] = sum_h Y[h] e^{+2pi i p h/14} -> LDS A view ----
#pragma unroll
    for (int i2 = 0; i2 < 7; ++i2) {
      evr[i2] = Yr[2 * i2];     evi[i2] = Yi[2 * i2];
      odr[i2] = Yr[2 * i2 + 1]; odi[i2] = Yi[2 * i2 + 1];
    }
    dft7<-1>(evr, evi, Er, Ei);
    dft7<-1>(odr, odi, Qr, Qi);
    float* Ap = &U[cur][cl * RST + w];
    Ap[0]          = Er[0] + Qr[0];  Ap[8]          = Ei[0] + Qi[0];
    Ap[7 * 16]     = Er[0] - Qr[0];  Ap[7 * 16 + 8] = Ei[0] - Qi[0];
#pragma unroll
    for (int p = 1; p < 7; ++p) {
      const float c = C14t[p], s = S14t[p];
      const float Tr = fmaf(Qr[p], c, -Qi[p] * s);   // conj(omega14^p) * O
      const float Ti = fmaf(Qi[p], c,  Qr[p] * s);
      Ap[p * 16]           = Er[p] + Tr;  Ap[p * 16 + 8]       = Ei[p] + Ti;
      Ap[(p + 7) * 16]     = Er[p] - Tr;  Ap[(p + 7) * 16 + 8] = Ei[p] - Ti;
    }

    // write next tile's S into the other buffer (vmcnt wait lands here, ~1500cy
    // after issue -> HBM latency fully hidden under stages 2-4)
    if (t + 1 < NB) stage_write(cur ^ 1);

    __syncthreads();   // B2: A(t) visible; S(t+1) staged

    // ---- epilogue: thread per (p,c); q<->14-q symmetry shares cos/sin sums ----
    float* ob = out + (size_t)(b0 + t) * (Nn * Cc) + c0;
#pragma unroll
    for (int r = 0; r < 2; ++r) {
      const int e = tid + r * TPB;
      if (e < 14 * CT) {
        const int c2 = e & 15, p = e >> 4;
        const float* ap = &U[cur][c2 * RST + p * 16];
        float a[16];
        *reinterpret_cast<float4*>(&a[0])  = *reinterpret_cast<const float4*>(&ap[0]);
        *reinterpret_cast<float4*>(&a[4])  = *reinterpret_cast<const float4*>(&ap[4]);
        *reinterpret_cast<float4*>(&a[8])  = *reinterpret_cast<const float4*>(&ap[8]);
        *reinterpret_cast<float4*>(&a[12]) = *reinterpret_cast<const float4*>(&ap[12]);
        float* op = ob + (p * 14) * Cc + c2;
        op[0]       = ((a[0] + a[7]) + (a[1] + a[2])) + ((a[3] + a[4]) + (a[5] + a[6]));
        op[7 * Cc]  = ((a[0] - a[7]) - (a[1] - a[2])) - ((a[3] - a[4]) + (a[5] - a[6]));
#pragma unroll
        for (int q = 1; q < 7; ++q) {
          float cs = (q & 1) ? (a[0] - a[7]) : (a[0] + a[7]);
          float ss = 0.f;
#pragma unroll
          for (int w2 = 1; w2 < 7; ++w2) {
            cs = fmaf(a[w2], C14t[(w2 * q) % 14], cs);
            ss = fmaf(a[8 + w2], S14t[(w2 * q) % 14], ss);
          }
          op[q * Cc]        = cs - ss;
          op[(14 - q) * Cc] = cs + ss;
        }
      }
    }

    cur ^= 1;
  }
}

extern "C" void kernel_launch(void* const* d_in, const int* in_sizes, int n_in,
                              void* d_out, int out_size, void* d_ws, size_t ws_size,
                              hipStream_t stream) {
  const float* x  = (const float*)d_in[0];
  const float* wt = (const float*)d_in[1];
  float* out      = (float*)d_out;
  dim3 grid(Cc / CT, Bb / NB);
  gf_kernel<<<grid, TPB, 0, stream>>>(x, wt, out);
}